// Round 1
// baseline (388.746 us; speedup 1.0000x reference)
//
#include <hip/hip_runtime.h>

// SpikingLayer forward: first-spike times of a delayed-synapse LIF layer.
// B=128, I=512+1 bias, O=512, STEPS=200.
// Strategy: 1 wave per (batch, 64-output tile). Each lane owns one (b,o):
//   Phase 1: bin 513 synapse charges into a private LDS column charge[t][lane]
//            (bank = lane%32 -> 2-way conflict = free; ds_add_f32 keeps
//            i-ascending add order per lane => bit-exact vs numpy scatter-add).
//   Phase 2: 200-step leaky integration with first-crossing interpolation,
//            wave-uniform early exit once all 64 lanes spiked.
// Numerics replicate numpy exactly: IEEE f32 division (no fast recip),
// v_cvt_i32_f32 RNE == np.round().astype(int32), fp contract OFF (no FMA).

#define IN_F    512
#define OUT_F   512
#define NIN     513
#define BATCH   128
#define STEPS   200
#define RES_F   1e-4f
// double exp(-1e-4/5e-3) = exp(-0.02), rounded to f32 by the literal:
#define DECAY_F 0.98019867330675525f
// double (1.0 - exp(-0.02)), rounded to f32:
#define ONEMD_F 0.019801326693244747f
#define SIM_T_F 2e-2f

__global__ __launch_bounds__(64) void snn_fwd(
    const float* __restrict__ input_times,   // [B, IN_F]
    const float* __restrict__ weights,       // [NIN, OUT_F]
    const float* __restrict__ delays,        // [NIN, OUT_F]
    const float* __restrict__ thresholds,    // [OUT_F]
    float* __restrict__ out)                 // [B, OUT_F]
{
#pragma clang fp contract(off)
    __shared__ float charge[STEPS * 64];     // [step][lane], 51200 B
    __shared__ float times_s[NIN];

    const int lane  = threadIdx.x;           // 0..63
    const int b     = blockIdx.x >> 3;       // batch index
    const int otile = blockIdx.x & 7;        // 8 tiles of 64 outputs
    const int o     = (otile << 6) + lane;

    // --- zero charge bins (float4 LDS stores) ---
    {
        float4 z = make_float4(0.f, 0.f, 0.f, 0.f);
        float4* c4 = (float4*)charge;
        #pragma unroll
        for (int k = lane; k < STEPS * 16; k += 64) c4[k] = z;
    }
    // --- stage this batch's input times (+ bias spike at t=0) ---
    for (int i = lane; i < IN_F; i += 64)
        times_s[i] = input_times[b * IN_F + i];
    if (lane == 0) times_s[IN_F] = 0.f;
    __syncthreads();

    // --- Phase 1: bin synapse charges ---
    const float* __restrict__ wp = weights + o;
    const float* __restrict__ dp = delays  + o;
    #pragma unroll 4
    for (int i = 0; i < NIN; ++i) {
        float ti = times_s[i];               // LDS broadcast
        float dl = dp[i * OUT_F];            // coalesced, L2-hot
        float w  = wp[i * OUT_F];
        float arrival = ti + dl;
        // IEEE f32 divide + round-nearest-even cvt == np.round(a/RES).astype(i32)
        int s = __float2int_rn(arrival / RES_F);
        s = s < 0 ? 0 : (s > STEPS - 1 ? STEPS - 1 : s);
        atomicAdd(&charge[(s << 6) + lane], w);   // ds_add_f32, per-lane i-order
    }
    __syncthreads();

    // --- Phase 2: leaky integration, first threshold crossing ---
    const float thr = thresholds[o];
    float syn = 0.f, mem = 0.f, spike_t = SIM_T_F, tf = 0.f;
    bool spiked = false;
    for (int t = 0; t < STEPS; ++t) {
        float c     = charge[(t << 6) + lane];
        float syn_n = syn * DECAY_F + c;                 // mul+add, no fma
        float mem_n = mem * DECAY_F + ONEMD_F * syn_n;   // mul,mul,add, no fma
        if (!spiked && mem_n >= thr) {
            float denom = mem_n - mem;
            float safe  = fabsf(denom) > 1e-12f ? denom : 1e-12f;
            float frac  = (thr - mem) / safe;
            frac = frac < 0.f ? 0.f : (frac > 1.f ? 1.f : frac);
            spike_t = (tf + frac) * RES_F;
            spiked  = true;
        }
        syn = syn_n; mem = mem_n; tf += 1.f;
        if (__all(spiked)) break;            // all lanes done -> skip tail steps
    }
    out[b * OUT_F + o] = spike_t;
}

extern "C" void kernel_launch(void* const* d_in, const int* in_sizes, int n_in,
                              void* d_out, int out_size, void* d_ws, size_t ws_size,
                              hipStream_t stream) {
    const float* input_times = (const float*)d_in[0];   // [128, 512]
    const float* weights     = (const float*)d_in[1];   // [513, 512]
    const float* delays      = (const float*)d_in[2];   // [513, 512]
    const float* thresholds  = (const float*)d_in[3];   // [512]
    float* out = (float*)d_out;                         // [128, 512]

    dim3 grid(BATCH * (OUT_F / 64));   // 1024 blocks, 1 wave each
    snn_fwd<<<grid, 64, 0, stream>>>(input_times, weights, delays, thresholds, out);
}

// Round 2
// 234.783 us; speedup vs baseline: 1.6558x; 1.6558x over previous
//
#include <hip/hip_runtime.h>

// SpikingLayer forward: first-spike times of a delayed-synapse LIF layer.
// B=128, I=512+1 bias, O=512, STEPS=200.
// R1: 388us -> target ~15us. Root cause of R0: 1-wave blocks (2 waves/CU) +
// serialized per-iteration L3-latency loads (W+D = 4.2MB > 4MB per-XCD L2).
// Now: 256-thr blocks (4 waves) per (b, 64-o tile); 512 synapses split
// 128/wave; explicit depth-8 register double-buffer keeps >=8 loads in
// flight; phase 2 (exact sequential scan) on wave 0 with 4-ahead LDS reads.
// Numerics: IEEE f32 div, RNE cvt, contract off => matches numpy per-op.
// Cross-wave ds_add order in a bin is nondeterministic: ~1e-8 charge
// perturbation, spike-time interpolation is continuous across a bin flip.

#define IN_F    512
#define OUT_F   512
#define BATCH   128
#define STEPS   200
#define RES_F   1e-4f
// double exp(-1e-4/5e-3) = exp(-0.02), rounded to f32 by the literal:
#define DECAY_F 0.98019867330675525f
// double (1.0 - exp(-0.02)), rounded to f32:
#define ONEMD_F 0.019801326693244747f
#define SIM_T_F 2e-2f

__global__ __launch_bounds__(256) void snn_fwd(
    const float* __restrict__ input_times,   // [B, IN_F]
    const float* __restrict__ weights,       // [IN_F+1, OUT_F]
    const float* __restrict__ delays,        // [IN_F+1, OUT_F]
    const float* __restrict__ thresholds,    // [OUT_F]
    float* __restrict__ out)                 // [B, OUT_F]
{
#pragma clang fp contract(off)
    __shared__ float charge[STEPS * 64];     // [step][lane] 51200B; bank=lane%32, 2-way=free
    __shared__ float times_s[IN_F];

    const int tid  = threadIdx.x;
    const int wv   = tid >> 6;               // wave 0..3
    const int lane = tid & 63;
    const int b     = blockIdx.x >> 3;
    const int otile = blockIdx.x & 7;
    const int o     = (otile << 6) + lane;

    // zero charge bins (float4) + stage this batch's input times
    {
        float4 z = make_float4(0.f, 0.f, 0.f, 0.f);
        float4* c4 = (float4*)charge;
        for (int k = tid; k < STEPS * 16; k += 256) c4[k] = z;
    }
    for (int i = tid; i < IN_F; i += 256)
        times_s[i] = input_times[b * IN_F + i];
    __syncthreads();

    // --- Phase 1: bin synapse charges; 128 synapses per wave, depth-8 pipeline ---
    const float* __restrict__ wp = weights + o;
    const float* __restrict__ dp = delays  + o;
    const int i0 = wv << 7;                  // this wave's synapse range [i0, i0+128)

    float wb[2][8], db[2][8];
    #pragma unroll
    for (int j = 0; j < 8; ++j) {            // preload group 0 (16 loads in flight)
        wb[0][j] = wp[(i0 + j) * OUT_F];
        db[0][j] = dp[(i0 + j) * OUT_F];
    }
    for (int g = 0; g < 16; ++g) {
        const int cur = g & 1, nxt = cur ^ 1;
        if (g < 15) {                        // prefetch group g+1 while binning g
            const int ib = i0 + ((g + 1) << 3);
            #pragma unroll
            for (int j = 0; j < 8; ++j) {
                wb[nxt][j] = wp[(ib + j) * OUT_F];
                db[nxt][j] = dp[(ib + j) * OUT_F];
            }
        }
        const int ibase = i0 + (g << 3);
        #pragma unroll
        for (int j = 0; j < 8; ++j) {
            float ti  = times_s[ibase + j];            // wave-uniform LDS broadcast
            float arr = ti + db[cur][j];
            int s = __float2int_rn(arr / RES_F);       // IEEE div + RNE == np.round(a/RES)
            s = s < 0 ? 0 : (s > STEPS - 1 ? STEPS - 1 : s);
            atomicAdd(&charge[(s << 6) + lane], wb[cur][j]);   // ds_add_f32
        }
    }
    if (wv == 3) {                           // bias synapse i=512, spike time 0
        float dl = dp[IN_F * OUT_F];
        float wt = wp[IN_F * OUT_F];
        int s = __float2int_rn(dl / RES_F);
        s = s < 0 ? 0 : (s > STEPS - 1 ? STEPS - 1 : s);
        atomicAdd(&charge[(s << 6) + lane], wt);
    }
    __syncthreads();

    // --- Phase 2 (wave 0 only): exact sequential leaky integration ---
    if (wv == 0) {
        const float thr = thresholds[o];
        float syn = 0.f, mem = 0.f, spike_t = SIM_T_F;
        bool spiked = false;
        for (int t0 = 0; t0 < STEPS; t0 += 4) {
            float c[4];
            #pragma unroll
            for (int j = 0; j < 4; ++j)               // batch the ds_reads 4 ahead
                c[j] = charge[((t0 + j) << 6) + lane];
            #pragma unroll
            for (int j = 0; j < 4; ++j) {
                float syn_n = syn * DECAY_F + c[j];               // no fma
                float mem_n = mem * DECAY_F + ONEMD_F * syn_n;    // no fma
                if (!spiked && mem_n >= thr) {
                    float denom = mem_n - mem;
                    float safe  = fabsf(denom) > 1e-12f ? denom : 1e-12f;
                    float frac  = (thr - mem) / safe;
                    frac = frac < 0.f ? 0.f : (frac > 1.f ? 1.f : frac);
                    spike_t = ((float)(t0 + j) + frac) * RES_F;
                    spiked  = true;
                }
                syn = syn_n; mem = mem_n;
            }
            if (__all(spiked)) break;        // all 64 lanes latched -> skip tail
        }
        out[b * OUT_F + o] = spike_t;
    }
}

extern "C" void kernel_launch(void* const* d_in, const int* in_sizes, int n_in,
                              void* d_out, int out_size, void* d_ws, size_t ws_size,
                              hipStream_t stream) {
    const float* input_times = (const float*)d_in[0];   // [128, 512]
    const float* weights     = (const float*)d_in[1];   // [513, 512]
    const float* delays      = (const float*)d_in[2];   // [513, 512]
    const float* thresholds  = (const float*)d_in[3];   // [512]
    float* out = (float*)d_out;                         // [128, 512]

    dim3 grid(BATCH * (OUT_F / 64));   // 1024 blocks x 256 threads (4 waves)
    snn_fwd<<<grid, 256, 0, stream>>>(input_times, weights, delays, thresholds, out);
}

// Round 3
// 230.688 us; speedup vs baseline: 1.6852x; 1.0177x over previous
//
#include <hip/hip_runtime.h>

// SpikingLayer forward: first-spike times of a delayed-synapse LIF layer.
// B=128, I=512+1 bias, O=512, STEPS=200.
// R2: 181us -> target ~35us. R1 was ~88% stall (VALUBusy 11.5%) with VALU
// work itself only ~20us: the dynamic-indexed prefetch buffer defeated the
// load pipeline and each load carried only 4B/lane. Now:
//  - lane remap: lane owns 4 consecutive cols -> float4 W/D loads
//    (1KB/wave-instr, 4x fewer dependent steps)
//  - 8 waves/block (512thr), 64 rows/wave, 3 blocks/CU -> 24 waves/CU
//  - fully-unrolled static ping-pong pipeline, 2 f4-pairs deep (4KB in
//    flight per wave)
// Numerics replicate numpy per-op: IEEE f32 div, RNE cvt, contract off.
// ds_add ordering nondeterminism ~1e-8 charge perturbation (absmax 1.5e-5
// vs 1.05e-4 threshold in R1).

#define IN_F    512
#define OUT_F   512
#define BATCH   128
#define STEPS   200
#define RES_F   1e-4f
// double exp(-1e-4/5e-3) = exp(-0.02), rounded to f32 by the literal:
#define DECAY_F 0.98019867330675525f
// double (1.0 - exp(-0.02)), rounded to f32:
#define ONEMD_F 0.019801326693244747f
#define SIM_T_F 2e-2f

__global__ __launch_bounds__(512, 6) void snn_fwd(
    const float* __restrict__ input_times,   // [B, IN_F]
    const float* __restrict__ weights,       // [IN_F+1, OUT_F]
    const float* __restrict__ delays,        // [IN_F+1, OUT_F]
    const float* __restrict__ thresholds,    // [OUT_F]
    float* __restrict__ out)                 // [B, OUT_F]
{
#pragma clang fp contract(off)
    __shared__ float charge[STEPS * 64];     // [step][col] 51200B
    __shared__ float times_s[IN_F];

    const int tid  = threadIdx.x;
    const int wv   = tid >> 6;               // wave 0..7
    const int lane = tid & 63;
    const int b     = blockIdx.x >> 3;
    const int otile = blockIdx.x & 7;
    const int ob    = otile << 6;            // output-column base

    // zero charge bins (float4) + stage this batch's input times
    {
        float4 z = make_float4(0.f, 0.f, 0.f, 0.f);
        float4* c4 = (float4*)charge;
        #pragma unroll
        for (int k = tid; k < STEPS * 16; k += 512) c4[k] = z;
    }
    times_s[tid] = input_times[b * IN_F + tid];   // IN_F == blockDim ==512
    __syncthreads();

    // --- Phase 1: bin synapse charges ---
    // lane -> (row-offset sub, column-group cg): one float4 load covers
    // 4 rows x 64 cols per wave. Wave wv handles rows [64*wv, 64*wv+64).
    const int sub = lane >> 4;               // 0..3
    const int cg  = (lane & 15) << 2;        // 0,4,...,60
    const float4* __restrict__ Wp = (const float4*)weights;
    const float4* __restrict__ Dp = (const float4*)delays;
    const int r0   = wv << 6;                                // first row
    const int i0   = (r0 + sub) * (OUT_F / 4) + ((ob + cg) >> 2); // f4 index
    const int gstr = 4 * (OUT_F / 4);                        // 4 rows of f4s

    // bias row (i=512, spike time 0): wave 7, one column per lane
    if (wv == 7) {
        float dl = delays [IN_F * OUT_F + ob + lane];
        float wt = weights[IN_F * OUT_F + ob + lane];
        int s = __float2int_rn(dl / RES_F);
        s = s < 0 ? 0 : (s > STEPS - 1 ? STEPS - 1 : s);
        atomicAdd(&charge[(s << 6) + lane], wt);
    }

    // static depth-2 ping-pong over 16 f4-steps (fully unrolled)
    float4 wA = Wp[i0],            dA = Dp[i0];
    float4 wB = Wp[i0 + gstr],     dB = Dp[i0 + gstr];
    float  tA = times_s[r0 + sub];
    float  tB = times_s[r0 + 4 + sub];

    #pragma unroll
    for (int g = 0; g < 16; g += 2) {
        float4 wC = {}, dC = {}, wD = {}, dD = {};
        float  tC = 0.f, tD = 0.f;
        if (g + 2 < 16) {
            wC = Wp[i0 + (g + 2) * gstr]; dC = Dp[i0 + (g + 2) * gstr];
            tC = times_s[r0 + ((g + 2) << 2) + sub];
        }
        if (g + 3 < 16) {
            wD = Wp[i0 + (g + 3) * gstr]; dD = Dp[i0 + (g + 3) * gstr];
            tD = times_s[r0 + ((g + 3) << 2) + sub];
        }
        {   // consume step g
            const float* dv = (const float*)&dA;
            const float* wvp = (const float*)&wA;
            #pragma unroll
            for (int k = 0; k < 4; ++k) {
                float arr = tA + dv[k];
                int s = __float2int_rn(arr / RES_F);   // IEEE div + RNE
                s = s < 0 ? 0 : (s > STEPS - 1 ? STEPS - 1 : s);
                atomicAdd(&charge[(s << 6) + cg + k], wvp[k]);
            }
        }
        {   // consume step g+1
            const float* dv = (const float*)&dB;
            const float* wvp = (const float*)&wB;
            #pragma unroll
            for (int k = 0; k < 4; ++k) {
                float arr = tB + dv[k];
                int s = __float2int_rn(arr / RES_F);
                s = s < 0 ? 0 : (s > STEPS - 1 ? STEPS - 1 : s);
                atomicAdd(&charge[(s << 6) + cg + k], wvp[k]);
            }
        }
        wA = wC; dA = dC; tA = tC;
        wB = wD; dB = dD; tB = tD;
    }
    __syncthreads();

    // --- Phase 2 (wave 0 only): exact sequential leaky integration ---
    if (wv == 0) {
        const float thr = thresholds[ob + lane];
        float syn = 0.f, mem = 0.f, spike_t = SIM_T_F;
        bool spiked = false;
        for (int t0 = 0; t0 < STEPS; t0 += 4) {
            float c[4];
            #pragma unroll
            for (int j = 0; j < 4; ++j)               // batch the ds_reads
                c[j] = charge[((t0 + j) << 6) + lane];
            #pragma unroll
            for (int j = 0; j < 4; ++j) {
                float syn_n = syn * DECAY_F + c[j];               // no fma
                float mem_n = mem * DECAY_F + ONEMD_F * syn_n;    // no fma
                if (!spiked && mem_n >= thr) {
                    float denom = mem_n - mem;
                    float safe  = fabsf(denom) > 1e-12f ? denom : 1e-12f;
                    float frac  = (thr - mem) / safe;
                    frac = frac < 0.f ? 0.f : (frac > 1.f ? 1.f : frac);
                    spike_t = ((float)(t0 + j) + frac) * RES_F;
                    spiked  = true;
                }
                syn = syn_n; mem = mem_n;
            }
            if (__all(spiked)) break;        // all 64 lanes latched
        }
        out[b * OUT_F + ob + lane] = spike_t;
    }
}

extern "C" void kernel_launch(void* const* d_in, const int* in_sizes, int n_in,
                              void* d_out, int out_size, void* d_ws, size_t ws_size,
                              hipStream_t stream) {
    const float* input_times = (const float*)d_in[0];   // [128, 512]
    const float* weights     = (const float*)d_in[1];   // [513, 512]
    const float* delays      = (const float*)d_in[2];   // [513, 512]
    const float* thresholds  = (const float*)d_in[3];   // [512]
    float* out = (float*)d_out;                         // [128, 512]

    dim3 grid(BATCH * (OUT_F / 64));   // 1024 blocks x 512 threads (8 waves)
    snn_fwd<<<grid, 512, 0, stream>>>(input_times, weights, delays, thresholds, out);
}

// Round 4
// 83.475 us; speedup vs baseline: 4.6571x; 2.7636x over previous
//
#include <hip/hip_runtime.h>

// SpikingLayer forward: first-spike times of a delayed-synapse LIF layer.
// B=128, I=512+1 bias, O=512, STEPS=200.
// R3: R1 and R2 ran at identical speed (181/177us) across wildly different
// load structures & occupancy -> the invariant is 33.6M LDS fp atomicAdds
// at a measured ~3.2 cyc/lane-op wall (VALUBusy only 8.7%). Hypothesis:
// atomicAdd(float) on LDS lowers to a CAS loop. Fix: fixed-point
// ds_add_u32 (native, 1 instr, associative => deterministic binning).
//   w_int = rn(w * 2^23)  (exact pow2 mul; quant 6e-8; bin sums << 2^31)
//   charge stride 65 -> atomic bank = (s+col)%32, spread by random s.
// Bin-assignment math unchanged: IEEE f32 div + RNE cvt, contract off.

#define IN_F    512
#define OUT_F   512
#define BATCH   128
#define STEPS   200
#define RES_F   1e-4f
#define CSTRIDE 65                           // stride-65: bank=(s+col)%32
// double exp(-1e-4/5e-3) = exp(-0.02), rounded to f32 by the literal:
#define DECAY_F 0.98019867330675525f
// double (1.0 - exp(-0.02)), rounded to f32:
#define ONEMD_F 0.019801326693244747f
#define SIM_T_F 2e-2f
#define FPSCALE 8388608.0f                   // 2^23
#define INVSCALE 1.1920928955078125e-07f     // 2^-23, exact

__global__ __launch_bounds__(512, 6) void snn_fwd(
    const float* __restrict__ input_times,   // [B, IN_F]
    const float* __restrict__ weights,       // [IN_F+1, OUT_F]
    const float* __restrict__ delays,        // [IN_F+1, OUT_F]
    const float* __restrict__ thresholds,    // [OUT_F]
    float* __restrict__ out)                 // [B, OUT_F]
{
#pragma clang fp contract(off)
    __shared__ __align__(16) int chargeI[STEPS * CSTRIDE];   // 52000 B
    __shared__ float times_s[IN_F];

    const int tid  = threadIdx.x;
    const int wv   = tid >> 6;               // wave 0..7
    const int lane = tid & 63;
    const int b     = blockIdx.x >> 3;
    const int otile = blockIdx.x & 7;
    const int ob    = otile << 6;            // output-column base

    // zero charge bins (int4) + stage this batch's input times
    {
        int4 z = make_int4(0, 0, 0, 0);
        int4* c4 = (int4*)chargeI;
        #pragma unroll
        for (int k = tid; k < (STEPS * CSTRIDE) / 4; k += 512) c4[k] = z;
    }
    times_s[tid] = input_times[b * IN_F + tid];   // IN_F == blockDim == 512
    __syncthreads();

    // --- Phase 1: bin synapse charges ---
    // lane -> (row-offset sub, column-group cg): one float4 load covers
    // 4 rows x 64 cols per wave. Wave wv handles rows [64*wv, 64*wv+64).
    const int sub = lane >> 4;               // 0..3
    const int cg  = (lane & 15) << 2;        // 0,4,...,60
    const float4* __restrict__ Wp = (const float4*)weights;
    const float4* __restrict__ Dp = (const float4*)delays;
    const int r0   = wv << 6;                                // first row
    const int i0   = (r0 + sub) * (OUT_F / 4) + ((ob + cg) >> 2); // f4 index
    const int gstr = 4 * (OUT_F / 4);                        // 4 rows of f4s

    // bias row (i=512, spike time 0): wave 7, one column per lane
    if (wv == 7) {
        float dl = delays [IN_F * OUT_F + ob + lane];
        float wt = weights[IN_F * OUT_F + ob + lane];
        int s = __float2int_rn(dl / RES_F);
        s = s < 0 ? 0 : (s > STEPS - 1 ? STEPS - 1 : s);
        atomicAdd(&chargeI[s * CSTRIDE + lane], __float2int_rn(wt * FPSCALE));
    }

    // static depth-2 ping-pong over 16 f4-steps (fully unrolled)
    float4 wA = Wp[i0],            dA = Dp[i0];
    float4 wB = Wp[i0 + gstr],     dB = Dp[i0 + gstr];
    float  tA = times_s[r0 + sub];
    float  tB = times_s[r0 + 4 + sub];

    #pragma unroll
    for (int g = 0; g < 16; g += 2) {
        float4 wC = {}, dC = {}, wD = {}, dD = {};
        float  tC = 0.f, tD = 0.f;
        if (g + 2 < 16) {
            wC = Wp[i0 + (g + 2) * gstr]; dC = Dp[i0 + (g + 2) * gstr];
            tC = times_s[r0 + ((g + 2) << 2) + sub];
        }
        if (g + 3 < 16) {
            wD = Wp[i0 + (g + 3) * gstr]; dD = Dp[i0 + (g + 3) * gstr];
            tD = times_s[r0 + ((g + 3) << 2) + sub];
        }
        {   // consume step g
            const float* dv  = (const float*)&dA;
            const float* wvp = (const float*)&wA;
            #pragma unroll
            for (int k = 0; k < 4; ++k) {
                float arr = tA + dv[k];
                int s = __float2int_rn(arr / RES_F);   // IEEE div + RNE
                s = s < 0 ? 0 : (s > STEPS - 1 ? STEPS - 1 : s);
                atomicAdd(&chargeI[s * CSTRIDE + cg + k],
                          __float2int_rn(wvp[k] * FPSCALE));   // ds_add_u32
            }
        }
        {   // consume step g+1
            const float* dv  = (const float*)&dB;
            const float* wvp = (const float*)&wB;
            #pragma unroll
            for (int k = 0; k < 4; ++k) {
                float arr = tB + dv[k];
                int s = __float2int_rn(arr / RES_F);
                s = s < 0 ? 0 : (s > STEPS - 1 ? STEPS - 1 : s);
                atomicAdd(&chargeI[s * CSTRIDE + cg + k],
                          __float2int_rn(wvp[k] * FPSCALE));
            }
        }
        wA = wC; dA = dC; tA = tC;
        wB = wD; dB = dD; tB = tD;
    }
    __syncthreads();

    // --- Phase 2 (wave 0 only): exact sequential leaky integration ---
    if (wv == 0) {
        const float thr = thresholds[ob + lane];
        float syn = 0.f, mem = 0.f, spike_t = SIM_T_F;
        bool spiked = false;
        for (int t0 = 0; t0 < STEPS; t0 += 4) {
            float c[4];
            #pragma unroll
            for (int j = 0; j < 4; ++j)               // batch the ds_reads
                c[j] = (float)chargeI[(t0 + j) * CSTRIDE + lane] * INVSCALE;
            #pragma unroll
            for (int j = 0; j < 4; ++j) {
                float syn_n = syn * DECAY_F + c[j];               // no fma
                float mem_n = mem * DECAY_F + ONEMD_F * syn_n;    // no fma
                if (!spiked && mem_n >= thr) {
                    float denom = mem_n - mem;
                    float safe  = fabsf(denom) > 1e-12f ? denom : 1e-12f;
                    float frac  = (thr - mem) / safe;
                    frac = frac < 0.f ? 0.f : (frac > 1.f ? 1.f : frac);
                    spike_t = ((float)(t0 + j) + frac) * RES_F;
                    spiked  = true;
                }
                syn = syn_n; mem = mem_n;
            }
            if (__all(spiked)) break;        // all 64 lanes latched
        }
        out[b * OUT_F + ob + lane] = spike_t;
    }
}

extern "C" void kernel_launch(void* const* d_in, const int* in_sizes, int n_in,
                              void* d_out, int out_size, void* d_ws, size_t ws_size,
                              hipStream_t stream) {
    const float* input_times = (const float*)d_in[0];   // [128, 512]
    const float* weights     = (const float*)d_in[1];   // [513, 512]
    const float* delays      = (const float*)d_in[2];   // [513, 512]
    const float* thresholds  = (const float*)d_in[3];   // [512]
    float* out = (float*)d_out;                         // [128, 512]

    dim3 grid(BATCH * (OUT_F / 64));   // 1024 blocks x 512 threads (8 waves)
    snn_fwd<<<grid, 512, 0, stream>>>(input_times, weights, delays, thresholds, out);
}

// Round 6
// 78.906 us; speedup vs baseline: 4.9267x; 1.0579x over previous
//
#include <hip/hip_runtime.h>

// SpikingLayer forward: first-spike times of a delayed-synapse LIF layer.
// B=128, I=512+1 bias, O=512, STEPS=200.
// R5 = R4 with the RES_F placement bug fixed (define was below the kernel).
// R4 theory: R3's int-atomic switch confirmed the LDS fp-atomicAdd CAS wall
// (177 -> ~38us kernel). Remaining cost is the per-event IEEE f32 divide
// (~11 instr) + per-event weight fixed-point convert (recomputed 128x per
// weight). Changes vs R3:
//  - arr/1e-4f replaced by (float)((double)arr * 10000.0): f64 product is
//    EXACT (24+14 sig bits <= 53), f64->f32 cvt is RNE => bit-identical to
//    IEEE f32 division. ~11 instr -> 4.
//  - prologue kernel precomputes wI[i][o] = rn(w * 2^23) into d_ws once;
//    phase 1 loads int4 weights directly (binning deterministic: int adds).
//  - everything else as R3: stride-65 charge (bank=(s+col)%32), depth-2
//    load pipeline, exact sequential phase 2, wave-uniform early exit.

#define IN_F    512
#define OUT_F   512
#define BATCH   128
#define STEPS   200
#define RES_F   1e-4f
#define CSTRIDE 65                           // stride-65: bank=(s+col)%32
// double exp(-1e-4/5e-3) = exp(-0.02), rounded to f32 by the literal:
#define DECAY_F 0.98019867330675525f
// double (1.0 - exp(-0.02)), rounded to f32:
#define ONEMD_F 0.019801326693244747f
#define SIM_T_F 2e-2f
#define FPSCALE 8388608.0f                   // 2^23
#define INVSCALE 1.1920928955078125e-07f     // 2^-23, exact

// q = fl32(arr / 1e-4f) computed exactly: (double)arr*10000.0 is exact,
// double->float is RNE == the IEEE f32 division result, bit for bit.
__device__ __forceinline__ int bin_of(float arr) {
    float q = (float)((double)arr * 10000.0);
    int s = __float2int_rn(q);               // RNE == np.round half-to-even
    s = s < 0 ? 0 : (s > STEPS - 1 ? STEPS - 1 : s);
    return s;
}

__global__ __launch_bounds__(256) void prep_wi(
    const float* __restrict__ weights, int* __restrict__ wI)
{
    int idx = blockIdx.x * 256 + threadIdx.x;        // float4 index
    if (idx < (IN_F + 1) * OUT_F / 4) {
        float4 v = ((const float4*)weights)[idx];
        int4 r;
        r.x = __float2int_rn(v.x * FPSCALE);
        r.y = __float2int_rn(v.y * FPSCALE);
        r.z = __float2int_rn(v.z * FPSCALE);
        r.w = __float2int_rn(v.w * FPSCALE);
        ((int4*)wI)[idx] = r;
    }
}

__global__ __launch_bounds__(512, 6) void snn_fwd(
    const float* __restrict__ input_times,   // [B, IN_F]
    const int*   __restrict__ wI,            // [IN_F+1, OUT_F] fixed-point
    const float* __restrict__ delays,        // [IN_F+1, OUT_F]
    const float* __restrict__ thresholds,    // [OUT_F]
    float* __restrict__ out)                 // [B, OUT_F]
{
#pragma clang fp contract(off)
    __shared__ __align__(16) int chargeI[STEPS * CSTRIDE];   // 52000 B
    __shared__ float times_s[IN_F];

    const int tid  = threadIdx.x;
    const int wv   = tid >> 6;               // wave 0..7
    const int lane = tid & 63;
    const int b     = blockIdx.x >> 3;
    const int otile = blockIdx.x & 7;
    const int ob    = otile << 6;            // output-column base

    // zero charge bins (int4) + stage this batch's input times
    {
        int4 z = make_int4(0, 0, 0, 0);
        int4* c4 = (int4*)chargeI;
        #pragma unroll
        for (int k = tid; k < (STEPS * CSTRIDE) / 4; k += 512) c4[k] = z;
    }
    times_s[tid] = input_times[b * IN_F + tid];   // IN_F == blockDim == 512
    __syncthreads();

    // --- Phase 1: bin synapse charges ---
    // lane -> (row-offset sub, column-group cg): one 16B load covers
    // 4 rows x 64 cols per wave. Wave wv handles rows [64*wv, 64*wv+64).
    const int sub = lane >> 4;               // 0..3
    const int cg  = (lane & 15) << 2;        // 0,4,...,60
    const int4*   __restrict__ Wp = (const int4*)wI;
    const float4* __restrict__ Dp = (const float4*)delays;
    const int r0   = wv << 6;                                // first row
    const int i0   = (r0 + sub) * (OUT_F / 4) + ((ob + cg) >> 2); // vec4 index
    const int gstr = 4 * (OUT_F / 4);                        // 4 rows of vec4s

    // bias row (i=512, spike time 0): wave 7, one column per lane
    if (wv == 7) {
        float dl = delays[IN_F * OUT_F + ob + lane];
        int   wt = wI[IN_F * OUT_F + ob + lane];
        atomicAdd(&chargeI[bin_of(dl) * CSTRIDE + lane], wt);
    }

    // static depth-2 ping-pong over 16 vec4-steps (fully unrolled)
    int4   wA = Wp[i0],            wB = Wp[i0 + gstr];
    float4 dA = Dp[i0],            dB = Dp[i0 + gstr];
    float  tA = times_s[r0 + sub];
    float  tB = times_s[r0 + 4 + sub];

    #pragma unroll
    for (int g = 0; g < 16; g += 2) {
        int4   wC = {}, wD = {};
        float4 dC = {}, dD = {};
        float  tC = 0.f, tD = 0.f;
        if (g + 2 < 16) {
            wC = Wp[i0 + (g + 2) * gstr]; dC = Dp[i0 + (g + 2) * gstr];
            tC = times_s[r0 + ((g + 2) << 2) + sub];
        }
        if (g + 3 < 16) {
            wD = Wp[i0 + (g + 3) * gstr]; dD = Dp[i0 + (g + 3) * gstr];
            tD = times_s[r0 + ((g + 3) << 2) + sub];
        }
        {   // consume step g
            const float* dv = (const float*)&dA;
            const int*   wi = (const int*)&wA;
            #pragma unroll
            for (int k = 0; k < 4; ++k) {
                int s = bin_of(tA + dv[k]);
                atomicAdd(&chargeI[s * CSTRIDE + cg + k], wi[k]);  // ds_add_u32
            }
        }
        {   // consume step g+1
            const float* dv = (const float*)&dB;
            const int*   wi = (const int*)&wB;
            #pragma unroll
            for (int k = 0; k < 4; ++k) {
                int s = bin_of(tB + dv[k]);
                atomicAdd(&chargeI[s * CSTRIDE + cg + k], wi[k]);
            }
        }
        wA = wC; dA = dC; tA = tC;
        wB = wD; dB = dD; tB = tD;
    }
    __syncthreads();

    // --- Phase 2 (wave 0 only): exact sequential leaky integration ---
    if (wv == 0) {
        const float thr = thresholds[ob + lane];
        float syn = 0.f, mem = 0.f, spike_t = SIM_T_F;
        bool spiked = false;
        for (int t0 = 0; t0 < STEPS; t0 += 4) {
            float c[4];
            #pragma unroll
            for (int j = 0; j < 4; ++j)               // batch the ds_reads
                c[j] = (float)chargeI[(t0 + j) * CSTRIDE + lane] * INVSCALE;
            #pragma unroll
            for (int j = 0; j < 4; ++j) {
                float syn_n = syn * DECAY_F + c[j];               // no fma
                float mem_n = mem * DECAY_F + ONEMD_F * syn_n;    // no fma
                if (!spiked && mem_n >= thr) {
                    float denom = mem_n - mem;
                    float safe  = fabsf(denom) > 1e-12f ? denom : 1e-12f;
                    float frac  = (thr - mem) / safe;
                    frac = frac < 0.f ? 0.f : (frac > 1.f ? 1.f : frac);
                    spike_t = ((float)(t0 + j) + frac) * RES_F;
                    spiked  = true;
                }
                syn = syn_n; mem = mem_n;
            }
            if (__all(spiked)) break;        // all 64 lanes latched
        }
        out[b * OUT_F + ob + lane] = spike_t;
    }
}

extern "C" void kernel_launch(void* const* d_in, const int* in_sizes, int n_in,
                              void* d_out, int out_size, void* d_ws, size_t ws_size,
                              hipStream_t stream) {
    const float* input_times = (const float*)d_in[0];   // [128, 512]
    const float* weights     = (const float*)d_in[1];   // [513, 512]
    const float* delays      = (const float*)d_in[2];   // [513, 512]
    const float* thresholds  = (const float*)d_in[3];   // [512]
    float* out = (float*)d_out;                         // [128, 512]
    int*   wI  = (int*)d_ws;                            // [513, 512] fixed-pt

    // prologue: weights -> fixed-point (runs every call; deterministic)
    int nvec4 = (IN_F + 1) * OUT_F / 4;                 // 65664
    prep_wi<<<(nvec4 + 255) / 256, 256, 0, stream>>>(weights, wI);

    dim3 grid(BATCH * (OUT_F / 64));   // 1024 blocks x 512 threads (8 waves)
    snn_fwd<<<grid, 512, 0, stream>>>(input_times, wI, delays, thresholds, out);
}